// Round 1
// baseline (400.245 us; speedup 1.0000x reference)
//
#include <hip/hip_runtime.h>
#include <hip/hip_bf16.h>
#include <math.h>

typedef __attribute__((ext_vector_type(8))) short bf16x8;
typedef __attribute__((ext_vector_type(4))) float f32x4;

__device__ inline ushort f2bf(float x) {
  union { float f; unsigned u; } c; c.f = x;
  unsigned u = c.u;
  u += 0x7fffu + ((u >> 16) & 1u);   // RTNE for normal positive values
  return (ushort)(u >> 16);
}

// ---------------- fp32 -> bf16 conversion (I matrix) ----------------
__global__ __launch_bounds__(256) void conv_I_kernel(const float* __restrict__ in,
                                                     ushort* __restrict__ out, int n) {
  int i = (blockIdx.x * 256 + threadIdx.x) * 4;
  if (i + 3 < n) {
    float4 v = *(const float4*)(in + i);
    ushort4 o;
    o.x = f2bf(v.x); o.y = f2bf(v.y); o.z = f2bf(v.z); o.w = f2bf(v.w);
    *(ushort4*)(out + i) = o;
  }
}

// ------- adjacency fp32 -> bf16 + AN[r] = sum_q adj[r][q]*N[q] -------
__global__ __launch_bounds__(256) void conv_adj_an(const float* __restrict__ adj,
                                                   const float* __restrict__ Nv,
                                                   ushort* __restrict__ adjbf,
                                                   float* __restrict__ AN, int R) {
  const int r = blockIdx.x;
  const int tid = threadIdx.x;
  const float* row = adj + (size_t)r * R;
  ushort* orow = adjbf + (size_t)r * R;
  float acc = 0.f;
  for (int q0 = tid * 4; q0 < R; q0 += 256 * 4) {
    float4 v = *(const float4*)(row + q0);
    float4 nv = *(const float4*)(Nv + q0);
    acc += v.x * nv.x + v.y * nv.y + v.z * nv.z + v.w * nv.w;
    ushort4 o;
    o.x = f2bf(v.x); o.y = f2bf(v.y); o.z = f2bf(v.z); o.w = f2bf(v.w);
    *(ushort4*)(orow + q0) = o;
  }
  #pragma unroll
  for (int off = 32; off > 0; off >>= 1) acc += __shfl_down(acc, off, 64);
  __shared__ float red[4];
  if ((tid & 63) == 0) red[tid >> 6] = acc;
  __syncthreads();
  if (tid == 0) AN[r] = red[0] + red[1] + red[2] + red[3];
}

// ---------------- bf16 MFMA GEMM: C[t,r] = sum_q A[t,q]*B[r,q] ----------------
// A: [M][K] row-major bf16, B: [N][K] row-major bf16 (B^T form), C: [M][N] fp32
__global__ __launch_bounds__(256) void gemm_bt_kernel(const ushort* __restrict__ A,
                                                      const ushort* __restrict__ B,
                                                      float* __restrict__ C,
                                                      int M, int N, int K) {
  __shared__ __align__(16) ushort sA[128 * 32];
  __shared__ __align__(16) ushort sB[128 * 32];
  const int tid = threadIdx.x;
  const int bn = blockIdx.x, bm = blockIdx.y;
  const int wave = tid >> 6, lane = tid & 63;
  const int wm = (wave >> 1) * 64, wn = (wave & 1) * 64;   // 2x2 waves over 128x128
  const int srow = tid >> 1, scol = (tid & 1) * 16;        // staging: 16 elems/thread/tile
  const size_t Arow = (size_t)(bm * 128 + srow) * K + scol;
  const size_t Brow = (size_t)(bn * 128 + srow) * K + scol;
  const int fm = lane & 15, fk = (lane >> 4) * 8;          // MFMA A/B fragment coords

  f32x4 acc[4][4];
  #pragma unroll
  for (int i = 0; i < 4; ++i)
    #pragma unroll
    for (int j = 0; j < 4; ++j) acc[i][j] = (f32x4){0.f, 0.f, 0.f, 0.f};

  for (int k0 = 0; k0 < K; k0 += 32) {
    __syncthreads();
    uint4 a0 = *(const uint4*)(A + Arow + k0);
    uint4 a1 = *(const uint4*)(A + Arow + k0 + 8);
    uint4 b0 = *(const uint4*)(B + Brow + k0);
    uint4 b1 = *(const uint4*)(B + Brow + k0 + 8);
    *(uint4*)(sA + srow * 32 + scol) = a0;
    *(uint4*)(sA + srow * 32 + scol + 8) = a1;
    *(uint4*)(sB + srow * 32 + scol) = b0;
    *(uint4*)(sB + srow * 32 + scol + 8) = b1;
    __syncthreads();
    bf16x8 af[4], bfr[4];
    #pragma unroll
    for (int i = 0; i < 4; ++i)
      af[i] = *(const bf16x8*)(sA + (wm + i * 16 + fm) * 32 + fk);
    #pragma unroll
    for (int j = 0; j < 4; ++j)
      bfr[j] = *(const bf16x8*)(sB + (wn + j * 16 + fm) * 32 + fk);
    #pragma unroll
    for (int i = 0; i < 4; ++i)
      #pragma unroll
      for (int j = 0; j < 4; ++j)
        acc[i][j] = __builtin_amdgcn_mfma_f32_16x16x32_bf16(af[i], bfr[j], acc[i][j], 0, 0, 0);
  }

  const int cm = (lane >> 4) * 4, cn = lane & 15;  // C/D: col=lane&15, row=quad*4+reg
  #pragma unroll
  for (int i = 0; i < 4; ++i)
    #pragma unroll
    for (int j = 0; j < 4; ++j) {
      size_t base = (size_t)(bm * 128 + wm + i * 16 + cm) * N + (bn * 128 + wn + j * 16 + cn);
      #pragma unroll
      for (int v = 0; v < 4; ++v)
        C[base + (size_t)v * N] = acc[i][j][v];
    }
}

// ---------------- fused log-prob + reduction over t ----------------
__global__ __launch_bounds__(256) void logprob_kernel(
    const float* __restrict__ S, const float* __restrict__ E,
    const float* __restrict__ I, const float* __restrict__ T,
    const float* __restrict__ S_E, const float* __restrict__ E_I,
    const float* __restrict__ I_T, const float* __restrict__ I_U,
    const float* __restrict__ T_R, const float* __restrict__ T_D,
    const float* __restrict__ detr, const float* __restrict__ recr,
    const float* __restrict__ cont, const float* __restrict__ AI,
    const float* __restrict__ AN,
    const float* __restrict__ pldE, const float* __restrict__ pldI,
    const float* __restrict__ pldT, float* __restrict__ out, int D1, int R) {
  const int r = blockIdx.x * 256 + threadIdx.x;
  if (r >= R) return;
  const float dE = 1.f / (1.f + expf(-pldE[0]));
  const float dI = 1.f / (1.f + expf(-pldI[0]));
  const float dT = 1.f / (1.f + expf(-pldT[0]));
  const float an = AN[r];
  const float L2PI = 1.8378770664093453f;
  const float omE = 1.f - dE;
  const float omI = 1.f - dI;
  const float omT = 1.f - dT;
  float acc = 0.f;
  const int t0 = blockIdx.y * 16;
  const int t1 = min(t0 + 16, D1);
  for (int t = t0; t < t1; ++t) {
    const size_t idx = (size_t)t * R + r;
    {  // S flow, k=1, p = -expm1(-c*AI/AN)
      float n_ = S[idx];
      float p = -expm1f(-(cont[idx] * AI[idx]) / an);
      float m = n_ * p;
      float var = m * (1.f - p);
      float d = S_E[idx] - m;
      acc += __logf(var) + d * d / var;
    }
    {  // E flow, k=1, p = decay_E
      float n_ = E[idx];
      float m = n_ * dE;
      float var = m * omE;
      float d = E_I[idx] - m;
      acc += __logf(var) + d * d / var;
    }
    {  // I flow, k=2: p1=det*dI, p2=(1-det)*dI
      float n_ = I[idx];
      float de = detr[idx];
      float p1 = de * dI, p2 = (1.f - de) * dI;
      float d1 = I_T[idx] - n_ * p1;
      float d2 = I_U[idx] - n_ * p2;
      float den = n_ * p1 * p2 * omI;  // det2 = n_*den
      float quad = (d1 * d1 * p2 * (1.f - p2) + 2.f * d1 * d2 * p1 * p2 +
                    d2 * d2 * p1 * (1.f - p1)) / den;
      acc += __logf(n_ * den) + quad;
    }
    {  // T flow, k=2: p1=rec*dT, p2=(1-rec)*dT
      float n_ = T[idx];
      float re = recr[idx];
      float p1 = re * dT, p2 = (1.f - re) * dT;
      float d1 = T_R[idx] - n_ * p1;
      float d2 = T_D[idx] - n_ * p2;
      float den = n_ * p1 * p2 * omT;
      float quad = (d1 * d1 * p2 * (1.f - p2) + 2.f * d1 * d2 * p1 * p2 +
                    d2 * d2 * p1 * (1.f - p1)) / den;
      acc += __logf(n_ * den) + quad;
    }
  }
  // per-t constant: -0.5*(L2PI + L2PI + 2*L2PI + 2*L2PI) = -3*L2PI
  float partial = -0.5f * acc - 3.f * L2PI * (float)(t1 - t0);
  atomicAdd(&out[r], partial);
}

extern "C" void kernel_launch(void* const* d_in, const int* in_sizes, int n_in,
                              void* d_out, int out_size, void* d_ws, size_t ws_size,
                              hipStream_t stream) {
  const float* S    = (const float*)d_in[0];
  const float* E    = (const float*)d_in[1];
  const float* I    = (const float*)d_in[2];
  const float* T    = (const float*)d_in[3];
  const float* Nv   = (const float*)d_in[4];
  const float* S_E  = (const float*)d_in[5];
  const float* E_I  = (const float*)d_in[6];
  const float* I_T  = (const float*)d_in[7];
  const float* I_U  = (const float*)d_in[8];
  const float* T_R  = (const float*)d_in[9];
  const float* T_D  = (const float*)d_in[10];
  const float* adj  = (const float*)d_in[11];
  const float* ldE  = (const float*)d_in[12];
  const float* ldI  = (const float*)d_in[13];
  const float* ldT  = (const float*)d_in[14];
  const float* detr = (const float*)d_in[15];
  const float* recr = (const float*)d_in[16];
  const float* cont = (const float*)d_in[17];
  float* out = (float*)d_out;

  const int R  = in_sizes[4];       // 4096
  const int D  = in_sizes[0] / R;   // 1024
  const int D1 = D - 1;             // 1023

  // workspace layout
  char* ws = (char*)d_ws;
  ushort* adjbf = (ushort*)ws;                                  // R*R bf16
  ushort* Ibf   = (ushort*)(ws + (size_t)R * R * 2);            // D*R bf16
  float*  AIbuf = (float*)(ws + (size_t)R * R * 2 + (size_t)D * R * 2);  // D*R f32
  float*  ANbuf = (float*)((char*)AIbuf + (size_t)D * R * 4);   // R f32

  // 1. I -> bf16
  const int nI = D * R;
  hipLaunchKernelGGL(conv_I_kernel, dim3(nI / 4 / 256), dim3(256), 0, stream, I, Ibf, nI);
  // 2. adjacency -> bf16 + AN
  hipLaunchKernelGGL(conv_adj_an, dim3(R), dim3(256), 0, stream, adj, Nv, adjbf, ANbuf, R);
  // 3. AI[t,r] = sum_q I[t,q]*adj[r,q]   (M=D rows; row D-1 computed but unused)
  hipLaunchKernelGGL(gemm_bt_kernel, dim3(R / 128, D / 128), dim3(256), 0, stream,
                     Ibf, adjbf, AIbuf, D, R, R);
  // 4. zero output accumulator
  hipMemsetAsync(d_out, 0, (size_t)out_size * sizeof(float), stream);
  // 5. fused log-prob + reduction over t
  hipLaunchKernelGGL(logprob_kernel, dim3(R / 256, (D1 + 15) / 16), dim3(256), 0, stream,
                     S, E, I, T, S_E, E_I, I_T, I_U, T_R, T_D, detr, recr, cont,
                     AIbuf, ANbuf, ldE, ldI, ldT, out, D1, R);
}

// Round 2
// 385.142 us; speedup vs baseline: 1.0392x; 1.0392x over previous
//
#include <hip/hip_runtime.h>
#include <hip/hip_bf16.h>
#include <math.h>

typedef __attribute__((ext_vector_type(8))) short bf16x8;
typedef __attribute__((ext_vector_type(4))) float f32x4;
typedef unsigned int u32;

__device__ inline ushort f2bf(float x) {
  union { float f; unsigned u; } c; c.f = x;
  unsigned u = c.u;
  u += 0x7fffu + ((u >> 16) & 1u);   // RTNE
  return (ushort)(u >> 16);
}

// async global->LDS, 16B per lane; LDS dest = wave-uniform base + lane*16
__device__ __forceinline__ void gl_lds16(const ushort* g, ushort* l) {
  __builtin_amdgcn_global_load_lds(
      (const __attribute__((address_space(1))) u32*)g,
      (__attribute__((address_space(3))) u32*)l, 16, 0, 0);
}

// ---------------- fp32 -> bf16 conversion (I matrix) ----------------
__global__ __launch_bounds__(256) void conv_I_kernel(const float* __restrict__ in,
                                                     ushort* __restrict__ out, int n) {
  int i = (blockIdx.x * 256 + threadIdx.x) * 4;
  if (i + 3 < n) {
    float4 v = *(const float4*)(in + i);
    ushort4 o;
    o.x = f2bf(v.x); o.y = f2bf(v.y); o.z = f2bf(v.z); o.w = f2bf(v.w);
    *(ushort4*)(out + i) = o;
  }
}

// ------- adjacency fp32 -> bf16 + AN[r] = sum_q adj[r][q]*N[q] -------
__global__ __launch_bounds__(256) void conv_adj_an(const float* __restrict__ adj,
                                                   const float* __restrict__ Nv,
                                                   ushort* __restrict__ adjbf,
                                                   float* __restrict__ AN, int R) {
  const int r = blockIdx.x;
  const int tid = threadIdx.x;
  const float* row = adj + (size_t)r * R;
  ushort* orow = adjbf + (size_t)r * R;
  float acc = 0.f;
  for (int q0 = tid * 4; q0 < R; q0 += 256 * 4) {
    float4 v = *(const float4*)(row + q0);
    float4 nv = *(const float4*)(Nv + q0);
    acc += v.x * nv.x + v.y * nv.y + v.z * nv.z + v.w * nv.w;
    ushort4 o;
    o.x = f2bf(v.x); o.y = f2bf(v.y); o.z = f2bf(v.z); o.w = f2bf(v.w);
    *(ushort4*)(orow + q0) = o;
  }
  #pragma unroll
  for (int off = 32; off > 0; off >>= 1) acc += __shfl_down(acc, off, 64);
  __shared__ float red[4];
  if ((tid & 63) == 0) red[tid >> 6] = acc;
  __syncthreads();
  if (tid == 0) AN[r] = red[0] + red[1] + red[2] + red[3];
}

// -------- bf16 MFMA GEMM, m97 structure + split-K=2 via blockIdx.z --------
// A: [M][K] bf16 row-major, B: [N][K] bf16 row-major; C_z: [M][N] fp32
__global__ __launch_bounds__(256) void gemm_bt_lds(const ushort* __restrict__ A,
                                                   const ushort* __restrict__ B,
                                                   float* __restrict__ C,
                                                   int M, int N, int K, int Khalf) {
  __shared__ __align__(16) ushort sA[128 * 32];
  __shared__ __align__(16) ushort sB[128 * 32];
  const int tid = threadIdx.x;
  const int bn = blockIdx.x, bm = blockIdx.y, bz = blockIdx.z;
  const int wave = tid >> 6, lane = tid & 63;
  const int wm = (wave >> 1) * 64, wn = (wave & 1) * 64;   // 2x2 waves, 64x64 each

  // staging: wave w covers row-blocks p=2w,2w+1 (16 rows x 32 cols each)
  const int p0 = wave * 2, p1 = wave * 2 + 1;
  const int lrow = lane >> 2;              // [0,16)
  const int scol = (lane & 3) * 8;         // {0,8,16,24}
  const size_t kbase = (size_t)bz * Khalf + scol;
  const ushort* Ag0 = A + (size_t)(bm * 128 + p0 * 16 + lrow) * K + kbase;
  const ushort* Ag1 = A + (size_t)(bm * 128 + p1 * 16 + lrow) * K + kbase;
  const ushort* Bg0 = B + (size_t)(bn * 128 + p0 * 16 + lrow) * K + kbase;
  const ushort* Bg1 = B + (size_t)(bn * 128 + p1 * 16 + lrow) * K + kbase;
  ushort* sA0 = sA + p0 * 16 * 32;
  ushort* sA1 = sA + p1 * 16 * 32;
  ushort* sB0 = sB + p0 * 16 * 32;
  ushort* sB1 = sB + p1 * 16 * 32;

  const int fm = lane & 15, fk = (lane >> 4) * 8;   // MFMA A/B fragment coords

  f32x4 acc[4][4];
  #pragma unroll
  for (int i = 0; i < 4; ++i)
    #pragma unroll
    for (int j = 0; j < 4; ++j) acc[i][j] = (f32x4){0.f, 0.f, 0.f, 0.f};

  for (int k0 = 0; k0 < Khalf; k0 += 32) {
    __syncthreads();
    gl_lds16(Ag0 + k0, sA0);
    gl_lds16(Ag1 + k0, sA1);
    gl_lds16(Bg0 + k0, sB0);
    gl_lds16(Bg1 + k0, sB1);
    __syncthreads();   // drains vmcnt (global_load_lds) before use
    bf16x8 af[4], bfr[4];
    #pragma unroll
    for (int i = 0; i < 4; ++i)
      af[i] = *(const bf16x8*)(sA + (wm + i * 16 + fm) * 32 + fk);
    #pragma unroll
    for (int j = 0; j < 4; ++j)
      bfr[j] = *(const bf16x8*)(sB + (wn + j * 16 + fm) * 32 + fk);
    #pragma unroll
    for (int i = 0; i < 4; ++i)
      #pragma unroll
      for (int j = 0; j < 4; ++j)
        acc[i][j] = __builtin_amdgcn_mfma_f32_16x16x32_bf16(af[i], bfr[j], acc[i][j], 0, 0, 0);
  }

  float* Cz = C + (size_t)bz * M * N;
  const int cm = (lane >> 4) * 4, cn = lane & 15;   // C/D: col=lane&15, row=quad*4+reg
  #pragma unroll
  for (int i = 0; i < 4; ++i)
    #pragma unroll
    for (int j = 0; j < 4; ++j) {
      size_t base = (size_t)(bm * 128 + wm + i * 16 + cm) * N + (bn * 128 + wn + j * 16 + cn);
      #pragma unroll
      for (int v = 0; v < 4; ++v)
        Cz[base + (size_t)v * N] = acc[i][j][v];
    }
}

// ---------------- fused log-prob + reduction over t (float4 over r) ----------------
__device__ __forceinline__ float elem_ll(float Sv, float Ev, float Iv, float Tv,
                                         float sev, float eiv, float itv, float iuv,
                                         float trv, float tdv, float dev, float rev,
                                         float cov, float aiv, float an_,
                                         float dE, float omE, float dI, float omI,
                                         float dT, float omT) {
  float acc;
  {  // S flow, k=1, p = -expm1(-c*AI/AN)
    float p = -expm1f(-(cov * aiv) / an_);
    float m = Sv * p;
    float var = m * (1.f - p);
    float d = sev - m;
    acc = __logf(var) + d * d / var;
  }
  {  // E flow, k=1
    float m = Ev * dE;
    float var = m * omE;
    float d = eiv - m;
    acc += __logf(var) + d * d / var;
  }
  {  // I flow, k=2
    float p1 = dev * dI, p2 = (1.f - dev) * dI;
    float d1 = itv - Iv * p1;
    float d2 = iuv - Iv * p2;
    float den = Iv * p1 * p2 * omI;
    float quad = (d1 * d1 * p2 * (1.f - p2) + 2.f * d1 * d2 * p1 * p2 +
                  d2 * d2 * p1 * (1.f - p1)) / den;
    acc += __logf(Iv * den) + quad;
  }
  {  // T flow, k=2
    float p1 = rev * dT, p2 = (1.f - rev) * dT;
    float d1 = trv - Tv * p1;
    float d2 = tdv - Tv * p2;
    float den = Tv * p1 * p2 * omT;
    float quad = (d1 * d1 * p2 * (1.f - p2) + 2.f * d1 * d2 * p1 * p2 +
                  d2 * d2 * p1 * (1.f - p1)) / den;
    acc += __logf(Tv * den) + quad;
  }
  return acc;
}

__global__ __launch_bounds__(256) void logprob_kernel(
    const float* __restrict__ S, const float* __restrict__ E,
    const float* __restrict__ I, const float* __restrict__ T,
    const float* __restrict__ S_E, const float* __restrict__ E_I,
    const float* __restrict__ I_T, const float* __restrict__ I_U,
    const float* __restrict__ T_R, const float* __restrict__ T_D,
    const float* __restrict__ detr, const float* __restrict__ recr,
    const float* __restrict__ cont, const float* __restrict__ AI0,
    const float* __restrict__ AI1, const float* __restrict__ AN,
    const float* __restrict__ pldE, const float* __restrict__ pldI,
    const float* __restrict__ pldT, float* __restrict__ out, int D1, int R) {
  const int r0 = (blockIdx.x * 256 + threadIdx.x) * 4;
  if (r0 + 3 >= R + 3 - 3 && r0 >= R) return;
  const float dE = 1.f / (1.f + expf(-pldE[0]));
  const float dI = 1.f / (1.f + expf(-pldI[0]));
  const float dT = 1.f / (1.f + expf(-pldT[0]));
  const float omE = 1.f - dE, omI = 1.f - dI, omT = 1.f - dT;
  const float L2PI = 1.8378770664093453f;
  float4 an4 = *(const float4*)(AN + r0);
  float an_[4] = {an4.x, an4.y, an4.z, an4.w};
  float acc[4] = {0.f, 0.f, 0.f, 0.f};
  const int t0 = blockIdx.y * 16;
  const int t1 = min(t0 + 16, D1);
  for (int t = t0; t < t1; ++t) {
    const size_t idx = (size_t)t * R + r0;
    float4 Sv = *(const float4*)(S + idx);
    float4 Ev = *(const float4*)(E + idx);
    float4 Iv = *(const float4*)(I + idx);
    float4 Tv = *(const float4*)(T + idx);
    float4 se = *(const float4*)(S_E + idx);
    float4 ei = *(const float4*)(E_I + idx);
    float4 it = *(const float4*)(I_T + idx);
    float4 iu = *(const float4*)(I_U + idx);
    float4 tr = *(const float4*)(T_R + idx);
    float4 td = *(const float4*)(T_D + idx);
    float4 de = *(const float4*)(detr + idx);
    float4 re = *(const float4*)(recr + idx);
    float4 co = *(const float4*)(cont + idx);
    float4 a0 = *(const float4*)(AI0 + idx);
    float4 a1 = *(const float4*)(AI1 + idx);
    float ai[4] = {a0.x + a1.x, a0.y + a1.y, a0.z + a1.z, a0.w + a1.w};
    float Sa[4] = {Sv.x, Sv.y, Sv.z, Sv.w}, Ea[4] = {Ev.x, Ev.y, Ev.z, Ev.w};
    float Ia[4] = {Iv.x, Iv.y, Iv.z, Iv.w}, Ta[4] = {Tv.x, Tv.y, Tv.z, Tv.w};
    float sea[4] = {se.x, se.y, se.z, se.w}, eia[4] = {ei.x, ei.y, ei.z, ei.w};
    float ita[4] = {it.x, it.y, it.z, it.w}, iua[4] = {iu.x, iu.y, iu.z, iu.w};
    float tra[4] = {tr.x, tr.y, tr.z, tr.w}, tda[4] = {td.x, td.y, td.z, td.w};
    float dea[4] = {de.x, de.y, de.z, de.w}, rea[4] = {re.x, re.y, re.z, re.w};
    float coa[4] = {co.x, co.y, co.z, co.w};
    #pragma unroll
    for (int v = 0; v < 4; ++v)
      acc[v] += elem_ll(Sa[v], Ea[v], Ia[v], Ta[v], sea[v], eia[v], ita[v], iua[v],
                        tra[v], tda[v], dea[v], rea[v], coa[v], ai[v], an_[v],
                        dE, omE, dI, omI, dT, omT);
  }
  const float cterm = -3.f * L2PI * (float)(t1 - t0);
  #pragma unroll
  for (int v = 0; v < 4; ++v)
    atomicAdd(&out[r0 + v], -0.5f * acc[v] + cterm);
}

extern "C" void kernel_launch(void* const* d_in, const int* in_sizes, int n_in,
                              void* d_out, int out_size, void* d_ws, size_t ws_size,
                              hipStream_t stream) {
  const float* S    = (const float*)d_in[0];
  const float* E    = (const float*)d_in[1];
  const float* I    = (const float*)d_in[2];
  const float* T    = (const float*)d_in[3];
  const float* Nv   = (const float*)d_in[4];
  const float* S_E  = (const float*)d_in[5];
  const float* E_I  = (const float*)d_in[6];
  const float* I_T  = (const float*)d_in[7];
  const float* I_U  = (const float*)d_in[8];
  const float* T_R  = (const float*)d_in[9];
  const float* T_D  = (const float*)d_in[10];
  const float* adj  = (const float*)d_in[11];
  const float* ldE  = (const float*)d_in[12];
  const float* ldI  = (const float*)d_in[13];
  const float* ldT  = (const float*)d_in[14];
  const float* detr = (const float*)d_in[15];
  const float* recr = (const float*)d_in[16];
  const float* cont = (const float*)d_in[17];
  float* out = (float*)d_out;

  const int R  = in_sizes[4];       // 4096
  const int D  = in_sizes[0] / R;   // 1024
  const int D1 = D - 1;             // 1023

  // workspace layout: adjbf (R*R bf16) | Ibf (D*R bf16) | AI0,AI1 (D*R f32 each) | AN (R f32)
  char* ws = (char*)d_ws;
  ushort* adjbf = (ushort*)ws;
  ushort* Ibf   = (ushort*)(ws + (size_t)R * R * 2);
  float*  AIbuf = (float*)(ws + (size_t)R * R * 2 + (size_t)D * R * 2);
  float*  ANbuf = (float*)((char*)AIbuf + 2 * (size_t)D * R * 4);

  const int nI = D * R;
  hipLaunchKernelGGL(conv_I_kernel, dim3(nI / 4 / 256), dim3(256), 0, stream, I, Ibf, nI);
  hipLaunchKernelGGL(conv_adj_an, dim3(R), dim3(256), 0, stream, adj, Nv, adjbf, ANbuf, R);
  hipLaunchKernelGGL(gemm_bt_lds, dim3(R / 128, D / 128, 2), dim3(256), 0, stream,
                     Ibf, adjbf, AIbuf, D, R, R, R / 2);
  hipMemsetAsync(d_out, 0, (size_t)out_size * sizeof(float), stream);
  hipLaunchKernelGGL(logprob_kernel, dim3(R / 1024, (D1 + 15) / 16), dim3(256), 0, stream,
                     S, E, I, T, S_E, E_I, I_T, I_U, T_R, T_D, detr, recr, cont,
                     AIbuf, AIbuf + (size_t)D * R, ANbuf, ldE, ldI, ldT, out, D1, R);
}

// Round 3
// 379.754 us; speedup vs baseline: 1.0540x; 1.0142x over previous
//
#include <hip/hip_runtime.h>
#include <hip/hip_bf16.h>
#include <math.h>

typedef __attribute__((ext_vector_type(8))) short bf16x8;
typedef __attribute__((ext_vector_type(4))) float f32x4;
typedef unsigned int u32;

__device__ inline ushort f2bf(float x) {
  union { float f; unsigned u; } c; c.f = x;
  unsigned u = c.u;
  u += 0x7fffu + ((u >> 16) & 1u);   // RTNE
  return (ushort)(u >> 16);
}

// async global->LDS, 16B per lane; LDS dest = wave-uniform base + lane*16
__device__ __forceinline__ void gl_lds16(const ushort* g, ushort* l) {
  __builtin_amdgcn_global_load_lds(
      (const __attribute__((address_space(1))) u32*)g,
      (__attribute__((address_space(3))) u32*)l, 16, 0, 0);
}

// ---- fused: adjacency fp32->bf16 + AN (blocks [0,R)) and I fp32->bf16 (rest) ----
__global__ __launch_bounds__(256) void conv_fused(const float* __restrict__ adj,
                                                  const float* __restrict__ Nv,
                                                  const float* __restrict__ I,
                                                  ushort* __restrict__ adjbf,
                                                  ushort* __restrict__ Ibf,
                                                  float* __restrict__ AN,
                                                  int R, int nI) {
  const int bx = blockIdx.x;
  const int tid = threadIdx.x;
  if (bx < R) {
    const int r = bx;
    const float* row = adj + (size_t)r * R;
    ushort* orow = adjbf + (size_t)r * R;
    float acc = 0.f;
    for (int q0 = tid * 4; q0 < R; q0 += 256 * 4) {
      float4 v = *(const float4*)(row + q0);
      float4 nv = *(const float4*)(Nv + q0);
      acc += v.x * nv.x + v.y * nv.y + v.z * nv.z + v.w * nv.w;
      ushort4 o;
      o.x = f2bf(v.x); o.y = f2bf(v.y); o.z = f2bf(v.z); o.w = f2bf(v.w);
      *(ushort4*)(orow + q0) = o;
    }
    #pragma unroll
    for (int off = 32; off > 0; off >>= 1) acc += __shfl_down(acc, off, 64);
    __shared__ float red[4];
    if ((tid & 63) == 0) red[tid >> 6] = acc;
    __syncthreads();
    if (tid == 0) AN[r] = red[0] + red[1] + red[2] + red[3];
  } else {
    int i = ((bx - R) * 256 + tid) * 4;
    if (i + 3 < nI) {
      float4 v = *(const float4*)(I + i);
      ushort4 o;
      o.x = f2bf(v.x); o.y = f2bf(v.y); o.z = f2bf(v.z); o.w = f2bf(v.w);
      *(ushort4*)(Ibf + i) = o;
    }
  }
}

// -------- bf16 MFMA GEMM, global_load_lds staging, XOR-swizzled LDS, split-K --------
// A: [M][K] bf16 row-major, B: [N][K] bf16 row-major; C_z: [M][N] fp32 per split z
__global__ __launch_bounds__(256) void gemm_bt_lds(const ushort* __restrict__ A,
                                                   const ushort* __restrict__ B,
                                                   float* __restrict__ C,
                                                   int M, int N, int K, int Ksplit) {
  __shared__ __align__(16) ushort sA[128 * 32];
  __shared__ __align__(16) ushort sB[128 * 32];
  const int tid = threadIdx.x;
  const int bn = blockIdx.x, bm = blockIdx.y, bz = blockIdx.z;
  const int wave = tid >> 6, lane = tid & 63;
  const int wm = (wave >> 1) * 64, wn = (wave & 1) * 64;   // 2x2 waves, 64x64 each

  // staging: wave w stages row-blocks p0=2w, p1=2w+1 (16 rows x 32 cols each).
  // LDS dest is fixed (base + lane*16); swizzle the GLOBAL column block so that
  // LDS[row][blk] = global[row][blk ^ (row&3)] -> fragment reads become 2-way.
  const int p0 = wave * 2, p1 = wave * 2 + 1;
  const int lrow = lane >> 2;                        // [0,16)
  const int sblk = (lane & 3) ^ (lrow & 3);          // swizzled col block
  const int scol = sblk * 8;
  const size_t kbase = (size_t)bz * Ksplit + scol;
  const ushort* Ag0 = A + (size_t)(bm * 128 + p0 * 16 + lrow) * K + kbase;
  const ushort* Ag1 = A + (size_t)(bm * 128 + p1 * 16 + lrow) * K + kbase;
  const ushort* Bg0 = B + (size_t)(bn * 128 + p0 * 16 + lrow) * K + kbase;
  const ushort* Bg1 = B + (size_t)(bn * 128 + p1 * 16 + lrow) * K + kbase;
  ushort* sA0 = sA + p0 * 16 * 32;
  ushort* sA1 = sA + p1 * 16 * 32;
  ushort* sB0 = sB + p0 * 16 * 32;
  ushort* sB1 = sB + p1 * 16 * 32;

  const int fm = lane & 15;          // fragment row within 16
  const int fkb = lane >> 4;         // logical col block [0,4)
  // physical col block for row rm: fkb ^ (rm & 3); rm&3 == fm&3 for all i
  const int pblk = (fkb ^ (fm & 3)) * 8;

  f32x4 acc[4][4];
  #pragma unroll
  for (int i = 0; i < 4; ++i)
    #pragma unroll
    for (int j = 0; j < 4; ++j) acc[i][j] = (f32x4){0.f, 0.f, 0.f, 0.f};

  for (int k0 = 0; k0 < Ksplit; k0 += 32) {
    __syncthreads();
    gl_lds16(Ag0 + k0, sA0);
    gl_lds16(Ag1 + k0, sA1);
    gl_lds16(Bg0 + k0, sB0);
    gl_lds16(Bg1 + k0, sB1);
    __syncthreads();   // drains vmcnt before LDS use
    bf16x8 af[4], bfr[4];
    #pragma unroll
    for (int i = 0; i < 4; ++i)
      af[i] = *(const bf16x8*)(sA + (wm + i * 16 + fm) * 32 + pblk);
    #pragma unroll
    for (int j = 0; j < 4; ++j)
      bfr[j] = *(const bf16x8*)(sB + (wn + j * 16 + fm) * 32 + pblk);
    #pragma unroll
    for (int i = 0; i < 4; ++i)
      #pragma unroll
      for (int j = 0; j < 4; ++j)
        acc[i][j] = __builtin_amdgcn_mfma_f32_16x16x32_bf16(af[i], bfr[j], acc[i][j], 0, 0, 0);
  }

  float* Cz = C + (size_t)bz * M * N;
  const int cm = (lane >> 4) * 4, cn = lane & 15;   // C/D: col=lane&15, row=quad*4+reg
  #pragma unroll
  for (int i = 0; i < 4; ++i)
    #pragma unroll
    for (int j = 0; j < 4; ++j) {
      size_t base = (size_t)(bm * 128 + wm + i * 16 + cm) * N + (bn * 128 + wn + j * 16 + cn);
      #pragma unroll
      for (int v = 0; v < 4; ++v)
        Cz[base + (size_t)v * N] = acc[i][j][v];
    }
}

// ---------------- fused log-prob + reduction over t ----------------
__device__ __forceinline__ float elem_ll(float Sv, float Ev, float Iv, float Tv,
                                         float sev, float eiv, float itv, float iuv,
                                         float trv, float tdv, float dev, float rev,
                                         float cov, float aiv, float an_,
                                         float dE, float omE, float dI, float omI,
                                         float dT, float omT) {
  float acc;
  {  // S flow, k=1, p = -expm1(-c*AI/AN)
    float p = -expm1f(-(cov * aiv) / an_);
    float m = Sv * p;
    float var = m * (1.f - p);
    float d = sev - m;
    acc = __logf(var) + d * d / var;
  }
  {  // E flow, k=1
    float m = Ev * dE;
    float var = m * omE;
    float d = eiv - m;
    acc += __logf(var) + d * d / var;
  }
  {  // I flow, k=2
    float p1 = dev * dI, p2 = (1.f - dev) * dI;
    float d1 = itv - Iv * p1;
    float d2 = iuv - Iv * p2;
    float den = Iv * p1 * p2 * omI;
    float quad = (d1 * d1 * p2 * (1.f - p2) + 2.f * d1 * d2 * p1 * p2 +
                  d2 * d2 * p1 * (1.f - p1)) / den;
    acc += __logf(Iv * den) + quad;
  }
  {  // T flow, k=2
    float p1 = rev * dT, p2 = (1.f - rev) * dT;
    float d1 = trv - Tv * p1;
    float d2 = tdv - Tv * p2;
    float den = Tv * p1 * p2 * omT;
    float quad = (d1 * d1 * p2 * (1.f - p2) + 2.f * d1 * d2 * p1 * p2 +
                  d2 * d2 * p1 * (1.f - p1)) / den;
    acc += __logf(Tv * den) + quad;
  }
  return acc;
}

template <int NS>
__global__ __launch_bounds__(256) void logprob_kernel(
    const float* __restrict__ S, const float* __restrict__ E,
    const float* __restrict__ I, const float* __restrict__ T,
    const float* __restrict__ S_E, const float* __restrict__ E_I,
    const float* __restrict__ I_T, const float* __restrict__ I_U,
    const float* __restrict__ T_R, const float* __restrict__ T_D,
    const float* __restrict__ detr, const float* __restrict__ recr,
    const float* __restrict__ cont, const float* __restrict__ AI,
    const float* __restrict__ AN,
    const float* __restrict__ pldE, const float* __restrict__ pldI,
    const float* __restrict__ pldT, float* __restrict__ out, int D1, int R) {
  const int r0 = (blockIdx.x * 256 + threadIdx.x) * 4;
  const size_t sstride = (size_t)(D1 + 1) * R;  // D*R per split
  const float dE = 1.f / (1.f + expf(-pldE[0]));
  const float dI = 1.f / (1.f + expf(-pldI[0]));
  const float dT = 1.f / (1.f + expf(-pldT[0]));
  const float omE = 1.f - dE, omI = 1.f - dI, omT = 1.f - dT;
  const float L2PI = 1.8378770664093453f;
  float4 an4 = *(const float4*)(AN + r0);
  float an_[4] = {an4.x, an4.y, an4.z, an4.w};
  float acc[4] = {0.f, 0.f, 0.f, 0.f};
  const int t0 = blockIdx.y * 2;
  const int t1 = min(t0 + 2, D1);
  for (int t = t0; t < t1; ++t) {
    const size_t idx = (size_t)t * R + r0;
    float4 Sv = *(const float4*)(S + idx);
    float4 Ev = *(const float4*)(E + idx);
    float4 Iv = *(const float4*)(I + idx);
    float4 Tv = *(const float4*)(T + idx);
    float4 se = *(const float4*)(S_E + idx);
    float4 ei = *(const float4*)(E_I + idx);
    float4 it = *(const float4*)(I_T + idx);
    float4 iu = *(const float4*)(I_U + idx);
    float4 tr = *(const float4*)(T_R + idx);
    float4 td = *(const float4*)(T_D + idx);
    float4 de = *(const float4*)(detr + idx);
    float4 re = *(const float4*)(recr + idx);
    float4 co = *(const float4*)(cont + idx);
    float ai[4] = {0.f, 0.f, 0.f, 0.f};
    #pragma unroll
    for (int s = 0; s < NS; ++s) {
      float4 a = *(const float4*)(AI + s * sstride + idx);
      ai[0] += a.x; ai[1] += a.y; ai[2] += a.z; ai[3] += a.w;
    }
    float Sa[4] = {Sv.x, Sv.y, Sv.z, Sv.w}, Ea[4] = {Ev.x, Ev.y, Ev.z, Ev.w};
    float Ia[4] = {Iv.x, Iv.y, Iv.z, Iv.w}, Ta[4] = {Tv.x, Tv.y, Tv.z, Tv.w};
    float sea[4] = {se.x, se.y, se.z, se.w}, eia[4] = {ei.x, ei.y, ei.z, ei.w};
    float ita[4] = {it.x, it.y, it.z, it.w}, iua[4] = {iu.x, iu.y, iu.z, iu.w};
    float tra[4] = {tr.x, tr.y, tr.z, tr.w}, tda[4] = {td.x, td.y, td.z, td.w};
    float dea[4] = {de.x, de.y, de.z, de.w}, rea[4] = {re.x, re.y, re.z, re.w};
    float coa[4] = {co.x, co.y, co.z, co.w};
    #pragma unroll
    for (int v = 0; v < 4; ++v)
      acc[v] += elem_ll(Sa[v], Ea[v], Ia[v], Ta[v], sea[v], eia[v], ita[v], iua[v],
                        tra[v], tda[v], dea[v], rea[v], coa[v], ai[v], an_[v],
                        dE, omE, dI, omI, dT, omT);
  }
  const float cterm = -3.f * L2PI * (float)(t1 - t0);
  #pragma unroll
  for (int v = 0; v < 4; ++v)
    atomicAdd(&out[r0 + v], -0.5f * acc[v] + cterm);
}

extern "C" void kernel_launch(void* const* d_in, const int* in_sizes, int n_in,
                              void* d_out, int out_size, void* d_ws, size_t ws_size,
                              hipStream_t stream) {
  const float* S    = (const float*)d_in[0];
  const float* E    = (const float*)d_in[1];
  const float* I    = (const float*)d_in[2];
  const float* T    = (const float*)d_in[3];
  const float* Nv   = (const float*)d_in[4];
  const float* S_E  = (const float*)d_in[5];
  const float* E_I  = (const float*)d_in[6];
  const float* I_T  = (const float*)d_in[7];
  const float* I_U  = (const float*)d_in[8];
  const float* T_R  = (const float*)d_in[9];
  const float* T_D  = (const float*)d_in[10];
  const float* adj  = (const float*)d_in[11];
  const float* ldE  = (const float*)d_in[12];
  const float* ldI  = (const float*)d_in[13];
  const float* ldT  = (const float*)d_in[14];
  const float* detr = (const float*)d_in[15];
  const float* recr = (const float*)d_in[16];
  const float* cont = (const float*)d_in[17];
  float* out = (float*)d_out;

  const int R  = in_sizes[4];       // 4096
  const int D  = in_sizes[0] / R;   // 1024
  const int D1 = D - 1;             // 1023

  // workspace: adjbf (R*R bf16) | Ibf (D*R bf16) | AI x NS (D*R f32 each) | AN (R f32)
  char* ws = (char*)d_ws;
  ushort* adjbf = (ushort*)ws;
  ushort* Ibf   = (ushort*)(ws + (size_t)R * R * 2);
  float*  AIbuf = (float*)(ws + (size_t)R * R * 2 + (size_t)D * R * 2);
  const size_t need4 = (size_t)R * R * 2 + (size_t)D * R * 2 +
                       4 * (size_t)D * R * 4 + (size_t)R * 4;
  const int NS = (ws_size >= need4) ? 4 : 2;
  float* ANbuf = (float*)((char*)AIbuf + (size_t)NS * D * R * 4);

  const int nI = D * R;
  const int convBlocks = R + nI / (256 * 4);
  hipLaunchKernelGGL(conv_fused, dim3(convBlocks), dim3(256), 0, stream,
                     adj, Nv, I, adjbf, Ibf, ANbuf, R, nI);
  hipLaunchKernelGGL(gemm_bt_lds, dim3(R / 128, D / 128, NS), dim3(256), 0, stream,
                     Ibf, adjbf, AIbuf, D, R, R, R / NS);
  hipMemsetAsync(d_out, 0, (size_t)out_size * sizeof(float), stream);
  if (NS == 4) {
    hipLaunchKernelGGL(logprob_kernel<4>, dim3(R / 1024, (D1 + 1) / 2), dim3(256), 0, stream,
                       S, E, I, T, S_E, E_I, I_T, I_U, T_R, T_D, detr, recr, cont,
                       AIbuf, ANbuf, ldE, ldI, ldT, out, D1, R);
  } else {
    hipLaunchKernelGGL(logprob_kernel<2>, dim3(R / 1024, (D1 + 1) / 2), dim3(256), 0, stream,
                       S, E, I, T, S_E, E_I, I_T, I_U, T_R, T_D, detr, recr, cont,
                       AIbuf, ANbuf, ldE, ldI, ldT, out, D1, R);
  }
}

// Round 4
// 353.571 us; speedup vs baseline: 1.1320x; 1.0741x over previous
//
#include <hip/hip_runtime.h>
#include <hip/hip_bf16.h>
#include <math.h>

typedef __attribute__((ext_vector_type(8))) short bf16x8;
typedef __attribute__((ext_vector_type(4))) float f32x4;
typedef unsigned int u32;

__device__ inline ushort f2bf(float x) {
  union { float f; unsigned u; } c; c.f = x;
  unsigned u = c.u;
  u += 0x7fffu + ((u >> 16) & 1u);   // RTNE
  return (ushort)(u >> 16);
}

// async global->LDS, 16B per lane; LDS dest = wave-uniform base + lane*16
__device__ __forceinline__ void gl_lds16(const ushort* g, ushort* l) {
  __builtin_amdgcn_global_load_lds(
      (const __attribute__((address_space(1))) u32*)g,
      (__attribute__((address_space(3))) u32*)l, 16, 0, 0);
}

// ---- fused: adjacency fp32->bf16 + AN (blocks [0,R)) and I fp32->bf16 (rest) ----
__global__ __launch_bounds__(256) void conv_fused(const float* __restrict__ adj,
                                                  const float* __restrict__ Nv,
                                                  const float* __restrict__ I,
                                                  ushort* __restrict__ adjbf,
                                                  ushort* __restrict__ Ibf,
                                                  float* __restrict__ AN,
                                                  int R, int nI) {
  const int bx = blockIdx.x;
  const int tid = threadIdx.x;
  if (bx < R) {
    const int r = bx;
    const float* row = adj + (size_t)r * R;
    ushort* orow = adjbf + (size_t)r * R;
    float acc = 0.f;
    for (int q0 = tid * 4; q0 < R; q0 += 256 * 4) {
      float4 v = *(const float4*)(row + q0);
      float4 nv = *(const float4*)(Nv + q0);
      acc += v.x * nv.x + v.y * nv.y + v.z * nv.z + v.w * nv.w;
      ushort4 o;
      o.x = f2bf(v.x); o.y = f2bf(v.y); o.z = f2bf(v.z); o.w = f2bf(v.w);
      *(ushort4*)(orow + q0) = o;
    }
    #pragma unroll
    for (int off = 32; off > 0; off >>= 1) acc += __shfl_down(acc, off, 64);
    __shared__ float red[4];
    if ((tid & 63) == 0) red[tid >> 6] = acc;
    __syncthreads();
    if (tid == 0) AN[r] = red[0] + red[1] + red[2] + red[3];
  } else {
    int i = ((bx - R) * 256 + tid) * 4;
    if (i + 3 < nI) {
      float4 v = *(const float4*)(I + i);
      ushort4 o;
      o.x = f2bf(v.x); o.y = f2bf(v.y); o.z = f2bf(v.z); o.w = f2bf(v.w);
      *(ushort4*)(Ibf + i) = o;
    }
  }
}

// -------- bf16 MFMA GEMM, global_load_lds staging, XOR-swizzled LDS, split-K --------
// A: [M][K] bf16 row-major, B: [N][K] bf16 row-major; C_z: [M][N] fp32 per split z
__global__ __launch_bounds__(256) void gemm_bt_lds(const ushort* __restrict__ A,
                                                   const ushort* __restrict__ B,
                                                   float* __restrict__ C,
                                                   int M, int N, int K, int Ksplit) {
  __shared__ __align__(16) ushort sA[128 * 32];
  __shared__ __align__(16) ushort sB[128 * 32];
  const int tid = threadIdx.x;
  const int bn = blockIdx.x, bm = blockIdx.y, bz = blockIdx.z;
  const int wave = tid >> 6, lane = tid & 63;
  const int wm = (wave >> 1) * 64, wn = (wave & 1) * 64;   // 2x2 waves, 64x64 each

  const int p0 = wave * 2, p1 = wave * 2 + 1;
  const int lrow = lane >> 2;                        // [0,16)
  const int sblk = (lane & 3) ^ (lrow & 3);          // swizzled col block
  const int scol = sblk * 8;
  const size_t kbase = (size_t)bz * Ksplit + scol;
  const ushort* Ag0 = A + (size_t)(bm * 128 + p0 * 16 + lrow) * K + kbase;
  const ushort* Ag1 = A + (size_t)(bm * 128 + p1 * 16 + lrow) * K + kbase;
  const ushort* Bg0 = B + (size_t)(bn * 128 + p0 * 16 + lrow) * K + kbase;
  const ushort* Bg1 = B + (size_t)(bn * 128 + p1 * 16 + lrow) * K + kbase;
  ushort* sA0 = sA + p0 * 16 * 32;
  ushort* sA1 = sA + p1 * 16 * 32;
  ushort* sB0 = sB + p0 * 16 * 32;
  ushort* sB1 = sB + p1 * 16 * 32;

  const int fm = lane & 15;
  const int fkb = lane >> 4;
  const int pblk = (fkb ^ (fm & 3)) * 8;

  f32x4 acc[4][4];
  #pragma unroll
  for (int i = 0; i < 4; ++i)
    #pragma unroll
    for (int j = 0; j < 4; ++j) acc[i][j] = (f32x4){0.f, 0.f, 0.f, 0.f};

  for (int k0 = 0; k0 < Ksplit; k0 += 32) {
    __syncthreads();
    gl_lds16(Ag0 + k0, sA0);
    gl_lds16(Ag1 + k0, sA1);
    gl_lds16(Bg0 + k0, sB0);
    gl_lds16(Bg1 + k0, sB1);
    __syncthreads();
    bf16x8 af[4], bfr[4];
    #pragma unroll
    for (int i = 0; i < 4; ++i)
      af[i] = *(const bf16x8*)(sA + (wm + i * 16 + fm) * 32 + pblk);
    #pragma unroll
    for (int j = 0; j < 4; ++j)
      bfr[j] = *(const bf16x8*)(sB + (wn + j * 16 + fm) * 32 + pblk);
    #pragma unroll
    for (int i = 0; i < 4; ++i)
      #pragma unroll
      for (int j = 0; j < 4; ++j)
        acc[i][j] = __builtin_amdgcn_mfma_f32_16x16x32_bf16(af[i], bfr[j], acc[i][j], 0, 0, 0);
  }

  float* Cz = C + (size_t)bz * M * N;
  const int cm = (lane >> 4) * 4, cn = lane & 15;
  #pragma unroll
  for (int i = 0; i < 4; ++i)
    #pragma unroll
    for (int j = 0; j < 4; ++j) {
      size_t base = (size_t)(bm * 128 + wm + i * 16 + cm) * N + (bn * 128 + wn + j * 16 + cn);
      #pragma unroll
      for (int v = 0; v < 4; ++v)
        Cz[base + (size_t)v * N] = acc[i][j][v];
    }
}

// ---------------- fused log-prob: partial sums over t-chunks ----------------
__device__ __forceinline__ float elem_ll(float Sv, float Ev, float Iv, float Tv,
                                         float sev, float eiv, float itv, float iuv,
                                         float trv, float tdv, float dev, float rev,
                                         float cov, float aiv, float an_,
                                         float dE, float omE, float dI, float omI,
                                         float dT, float omT) {
  float acc;
  {  // S flow, k=1, p = -expm1(-c*AI/AN)
    float p = -expm1f(-(cov * aiv) / an_);
    float m = Sv * p;
    float var = m * (1.f - p);
    float d = sev - m;
    acc = __logf(var) + d * d / var;
  }
  {  // E flow, k=1
    float m = Ev * dE;
    float var = m * omE;
    float d = eiv - m;
    acc += __logf(var) + d * d / var;
  }
  {  // I flow, k=2
    float p1 = dev * dI, p2 = (1.f - dev) * dI;
    float d1 = itv - Iv * p1;
    float d2 = iuv - Iv * p2;
    float den = Iv * p1 * p2 * omI;
    float quad = (d1 * d1 * p2 * (1.f - p2) + 2.f * d1 * d2 * p1 * p2 +
                  d2 * d2 * p1 * (1.f - p1)) / den;
    acc += __logf(Iv * den) + quad;
  }
  {  // T flow, k=2
    float p1 = rev * dT, p2 = (1.f - rev) * dT;
    float d1 = trv - Tv * p1;
    float d2 = tdv - Tv * p2;
    float den = Tv * p1 * p2 * omT;
    float quad = (d1 * d1 * p2 * (1.f - p2) + 2.f * d1 * d2 * p1 * p2 +
                  d2 * d2 * p1 * (1.f - p1)) / den;
    acc += __logf(Tv * den) + quad;
  }
  return acc;
}

template <int NS>
__global__ __launch_bounds__(256) void logprob_kernel(
    const float* __restrict__ S, const float* __restrict__ E,
    const float* __restrict__ I, const float* __restrict__ T,
    const float* __restrict__ S_E, const float* __restrict__ E_I,
    const float* __restrict__ I_T, const float* __restrict__ I_U,
    const float* __restrict__ T_R, const float* __restrict__ T_D,
    const float* __restrict__ detr, const float* __restrict__ recr,
    const float* __restrict__ cont, const float* __restrict__ AI,
    const float* __restrict__ AN,
    const float* __restrict__ pldE, const float* __restrict__ pldI,
    const float* __restrict__ pldT, float* __restrict__ partial, int D1, int R) {
  const int r0 = (blockIdx.x * 256 + threadIdx.x) * 4;
  const size_t sstride = (size_t)(D1 + 1) * R;  // D*R per split
  const float dE = 1.f / (1.f + expf(-pldE[0]));
  const float dI = 1.f / (1.f + expf(-pldI[0]));
  const float dT = 1.f / (1.f + expf(-pldT[0]));
  const float omE = 1.f - dE, omI = 1.f - dI, omT = 1.f - dT;
  const float L2PI = 1.8378770664093453f;
  float4 an4 = *(const float4*)(AN + r0);
  float an_[4] = {an4.x, an4.y, an4.z, an4.w};
  float acc[4] = {0.f, 0.f, 0.f, 0.f};
  const int t0 = blockIdx.y * 4;
  const int t1 = min(t0 + 4, D1);
  for (int t = t0; t < t1; ++t) {
    const size_t idx = (size_t)t * R + r0;
    float4 Sv = *(const float4*)(S + idx);
    float4 Ev = *(const float4*)(E + idx);
    float4 Iv = *(const float4*)(I + idx);
    float4 Tv = *(const float4*)(T + idx);
    float4 se = *(const float4*)(S_E + idx);
    float4 ei = *(const float4*)(E_I + idx);
    float4 it = *(const float4*)(I_T + idx);
    float4 iu = *(const float4*)(I_U + idx);
    float4 tr = *(const float4*)(T_R + idx);
    float4 td = *(const float4*)(T_D + idx);
    float4 de = *(const float4*)(detr + idx);
    float4 re = *(const float4*)(recr + idx);
    float4 co = *(const float4*)(cont + idx);
    float ai[4] = {0.f, 0.f, 0.f, 0.f};
    #pragma unroll
    for (int s = 0; s < NS; ++s) {
      float4 a = *(const float4*)(AI + s * sstride + idx);
      ai[0] += a.x; ai[1] += a.y; ai[2] += a.z; ai[3] += a.w;
    }
    float Sa[4] = {Sv.x, Sv.y, Sv.z, Sv.w}, Ea[4] = {Ev.x, Ev.y, Ev.z, Ev.w};
    float Ia[4] = {Iv.x, Iv.y, Iv.z, Iv.w}, Ta[4] = {Tv.x, Tv.y, Tv.z, Tv.w};
    float sea[4] = {se.x, se.y, se.z, se.w}, eia[4] = {ei.x, ei.y, ei.z, ei.w};
    float ita[4] = {it.x, it.y, it.z, it.w}, iua[4] = {iu.x, iu.y, iu.z, iu.w};
    float tra[4] = {tr.x, tr.y, tr.z, tr.w}, tda[4] = {td.x, td.y, td.z, td.w};
    float dea[4] = {de.x, de.y, de.z, de.w}, rea[4] = {re.x, re.y, re.z, re.w};
    float coa[4] = {co.x, co.y, co.z, co.w};
    #pragma unroll
    for (int v = 0; v < 4; ++v)
      acc[v] += elem_ll(Sa[v], Ea[v], Ia[v], Ta[v], sea[v], eia[v], ita[v], iua[v],
                        tra[v], tda[v], dea[v], rea[v], coa[v], ai[v], an_[v],
                        dE, omE, dI, omI, dT, omT);
  }
  const float cterm = -3.f * L2PI * (float)(t1 - t0);
  float4 res;
  res.x = -0.5f * acc[0] + cterm;
  res.y = -0.5f * acc[1] + cterm;
  res.z = -0.5f * acc[2] + cterm;
  res.w = -0.5f * acc[3] + cterm;
  *(float4*)(partial + (size_t)blockIdx.y * R + r0) = res;
}

// ---- final reduction: out[r] = sum_by partial[by][r], NBY rows ----
__global__ __launch_bounds__(256) void reduce_kernel(const float* __restrict__ part,
                                                     float* __restrict__ out,
                                                     int R, int NBY) {
  __shared__ float red[256];
  const int tid = threadIdx.x;
  const int r = blockIdx.x * 32 + (tid & 31);
  const int slice = tid >> 5;          // 8 slices over NBY
  const int rows = NBY >> 3;
  float acc = 0.f;
  for (int k = 0; k < rows; ++k)
    acc += part[(size_t)(slice * rows + k) * R + r];
  red[tid] = acc;
  __syncthreads();
  if (tid < 32) {
    float s = red[tid];
    #pragma unroll
    for (int sl = 1; sl < 8; ++sl) s += red[sl * 32 + tid];
    out[r] = s;
  }
}

extern "C" void kernel_launch(void* const* d_in, const int* in_sizes, int n_in,
                              void* d_out, int out_size, void* d_ws, size_t ws_size,
                              hipStream_t stream) {
  const float* S    = (const float*)d_in[0];
  const float* E    = (const float*)d_in[1];
  const float* I    = (const float*)d_in[2];
  const float* T    = (const float*)d_in[3];
  const float* Nv   = (const float*)d_in[4];
  const float* S_E  = (const float*)d_in[5];
  const float* E_I  = (const float*)d_in[6];
  const float* I_T  = (const float*)d_in[7];
  const float* I_U  = (const float*)d_in[8];
  const float* T_R  = (const float*)d_in[9];
  const float* T_D  = (const float*)d_in[10];
  const float* adj  = (const float*)d_in[11];
  const float* ldE  = (const float*)d_in[12];
  const float* ldI  = (const float*)d_in[13];
  const float* ldT  = (const float*)d_in[14];
  const float* detr = (const float*)d_in[15];
  const float* recr = (const float*)d_in[16];
  const float* cont = (const float*)d_in[17];
  float* out = (float*)d_out;

  const int R  = in_sizes[4];       // 4096
  const int D  = in_sizes[0] / R;   // 1024
  const int D1 = D - 1;             // 1023
  const int NBY = (D1 + 3) / 4;     // 256 t-chunks

  // ws: adjbf (R*R bf16) | Ibf (D*R bf16) | AI x NS (D*R f32) | AN (R f32) | partial (NBY*R f32)
  char* ws = (char*)d_ws;
  ushort* adjbf = (ushort*)ws;
  ushort* Ibf   = (ushort*)(ws + (size_t)R * R * 2);
  float*  AIbuf = (float*)(ws + (size_t)R * R * 2 + (size_t)D * R * 2);
  const size_t tail = (size_t)R * 4 + (size_t)NBY * R * 4;
  const size_t need4 = (size_t)R * R * 2 + (size_t)D * R * 2 +
                       4 * (size_t)D * R * 4 + tail;
  const int NS = (ws_size >= need4) ? 4 : 2;
  float* ANbuf   = (float*)((char*)AIbuf + (size_t)NS * D * R * 4);
  float* partial = ANbuf + R;

  const int nI = D * R;
  const int convBlocks = R + nI / (256 * 4);
  hipLaunchKernelGGL(conv_fused, dim3(convBlocks), dim3(256), 0, stream,
                     adj, Nv, I, adjbf, Ibf, ANbuf, R, nI);
  hipLaunchKernelGGL(gemm_bt_lds, dim3(R / 128, D / 128, NS), dim3(256), 0, stream,
                     Ibf, adjbf, AIbuf, D, R, R, R / NS);
  if (NS == 4) {
    hipLaunchKernelGGL(logprob_kernel<4>, dim3(R / 1024, NBY), dim3(256), 0, stream,
                       S, E, I, T, S_E, E_I, I_T, I_U, T_R, T_D, detr, recr, cont,
                       AIbuf, ANbuf, ldE, ldI, ldT, partial, D1, R);
  } else {
    hipLaunchKernelGGL(logprob_kernel<2>, dim3(R / 1024, NBY), dim3(256), 0, stream,
                       S, E, I, T, S_E, E_I, I_T, I_U, T_R, T_D, detr, recr, cont,
                       AIbuf, ANbuf, ldE, ldI, ldT, partial, D1, R);
  }
  hipLaunchKernelGGL(reduce_kernel, dim3(R / 32), dim3(256), 0, stream,
                     partial, out, R, NBY);
}